// Round 1
// 686.962 us; speedup vs baseline: 1.0032x; 1.0032x over previous
//
#include <hip/hip_runtime.h>

#define N_NODES 10000
#define E_EDGES 320000
#define KP 10016  // K padded to multiple of 32 for W split

typedef float f32x4 __attribute__((ext_vector_type(4)));
typedef __bf16 bf16x8 __attribute__((ext_vector_type(8)));

union frag_u { int4 i; bf16x8 b; };

static __device__ __forceinline__ ushort f2bf(float f) {
    unsigned u = __float_as_uint(f);
    unsigned r = (u + 0x7fffu + ((u >> 16) & 1u)) >> 16;  // RNE
    return (ushort)r;
}
static __device__ __forceinline__ float bf2f(ushort h) {
    return __uint_as_float(((unsigned)h) << 16);
}

// truncation split of two floats -> packed bf16 hi pair + lo pair (3 VALU/elem)
static __device__ __forceinline__ void split2(float f0, float f1,
                                              unsigned& hi, unsigned& lo) {
    unsigned u0 = __float_as_uint(f0), u1 = __float_as_uint(f1);
    hi = __builtin_amdgcn_perm(u1, u0, 0x07060302u);  // [f1.hi16 : f0.hi16]
    float h0 = __uint_as_float(u0 & 0xFFFF0000u);
    float h1 = __uint_as_float(u1 & 0xFFFF0000u);
    float l0 = f0 - h0, l1 = f1 - h1;  // exact residuals
    lo = __builtin_amdgcn_perm(__float_as_uint(l1), __float_as_uint(l0), 0x07060302u);
}

static __device__ __forceinline__ void load16_to_lds(const float* gp, void* lp) {
    __builtin_amdgcn_global_load_lds(
        (__attribute__((address_space(1))) void*)(gp),
        (__attribute__((address_space(3))) void*)(lp), 16, 0, 0);
}

// ---------------- fused: degree histogram + W1 split ----------------
// blocks [0,1250): histogram of dst.  blocks [1250,1250+2560): W1 -> bf16 hi/lo split.
// The two halves are data-independent; fusing removes one dispatch + tail.

#define HIST_BLOCKS (E_EDGES / 256)          // 1250
#define WSPLIT_KB   ((KP + 255) / 256)       // 40
#define WSPLIT_BLOCKS (WSPLIT_KB * 64)       // 2560

__global__ void k_hist_wsplit(const int* __restrict__ dst, int* __restrict__ deg,
                              const float* __restrict__ W1, ushort* __restrict__ Whi,
                              ushort* __restrict__ Wlo) {
    int bid = blockIdx.x;
    int tid = threadIdx.x;
    if (bid < HIST_BLOCKS) {
        int e = bid * 256 + tid;  // exact: 1250*256 == E_EDGES
        atomicAdd(&deg[dst[e]], 1);
    } else {
        int q = bid - HIST_BLOCKS;
        int n = q / WSPLIT_KB;
        int kb = q % WSPLIT_KB;
        int k = kb * 256 + tid;
        if (k >= KP) return;
        ushort h = 0, l = 0;
        if (k < N_NODES) {
            float f = W1[(long)k * 64 + n];
            h = f2bf(f);
            l = f2bf(f - bf2f(h));
        }
        Whi[(long)n * KP + k] = h;
        Wlo[(long)n * KP + k] = l;
    }
}

// ---------------- scan (+ dinv fused: same dependency point) ----------------

__global__ void k_scan(const int* __restrict__ deg, int* __restrict__ roff,
                       float* __restrict__ dinv) {
    __shared__ int sums[256];
    __shared__ int offs[256];
    const int CH = 40;
    int t = threadIdx.x;
    int base = t * CH;
    int s = 0;
    for (int i = 0; i < CH; i++) {
        int idx = base + i;
        if (idx < N_NODES) {
            int d = deg[idx];
            s += d;
            dinv[idx] = rsqrtf(1.0f + (float)d);  // +1 self-loop
        }
    }
    sums[t] = s;
    __syncthreads();
    if (t == 0) {
        int r = 0;
        for (int i = 0; i < 256; i++) { offs[i] = r; r += sums[i]; }
    }
    __syncthreads();
    int r = offs[t];
    for (int i = 0; i < CH; i++) {
        int idx = base + i;
        if (idx < N_NODES) { roff[idx] = r; r += deg[idx]; }
    }
    if (t == 255) roff[N_NODES] = E_EDGES;
}

__global__ void k_scatter(const int* __restrict__ src, const int* __restrict__ dst,
                          const int* __restrict__ roff, int* __restrict__ cursor,
                          const float* __restrict__ dinv,
                          int* __restrict__ csrc, float* __restrict__ cw) {
    int e = blockIdx.x * blockDim.x + threadIdx.x;
    if (e >= E_EDGES) return;
    int s = src[e], d = dst[e];
    int slot = roff[d] + atomicAdd(&cursor[d], 1);
    csrc[slot] = s;
    cw[slot] = dinv[s] * dinv[d];
}

// ---------------- GEMM1: split-bf16 MFMA, global_load_lds staging (unchanged) ----------------

#define G1_BM 128
#define G1_CHUNK 640
#define G1_NCHUNK 16  // 16*640 = 10240 >= KP

__global__ __launch_bounds__(256) void k_gemm1_mfma(
        const float* __restrict__ x, const ushort* __restrict__ Whi,
        const ushort* __restrict__ Wlo, float* __restrict__ out) {
    __shared__ float As32[G1_BM][32];
    __shared__ ushort Bs[2][64][40];  // hi/lo, rows padded to 80 B (bank-friendly)

    int tid = threadIdx.x;
    int lane = tid & 63, wv = tid >> 6;
    int quad = lane >> 4, lm = lane & 15;
    int m0 = blockIdx.x * G1_BM;
    int ks = blockIdx.y * G1_CHUNK;
    int ke = min(ks + G1_CHUNK, KP);

    int rown = lane >> 3;               // row within 8-row chunk
    int sp = (lane & 7) ^ rown;         // swizzled source k-piece
    long abase[4];
#pragma unroll
    for (int i = 0; i < 4; i++) {
        int row = (wv * 4 + i) * 8 + rown;
        int gm = min(m0 + row, N_NODES - 1);  // tail rows clamp (discarded at write)
        abase[i] = (long)gm * N_NODES + sp * 4;
    }
    const long FLAT_MAX = (long)N_NODES * N_NODES - 4;

    int bn = tid >> 2, bp = (tid & 3) * 8;
    const ushort* whip = Whi + (long)bn * KP + bp;
    const ushort* wlop = Wlo + (long)bn * KP + bp;

    f32x4 acc[2][4] = {};

    for (int k0 = ks; k0 < ke; k0 += 32) {
#pragma unroll
        for (int i = 0; i < 4; i++) {
            long flat = abase[i] + k0;
            if (flat > FLAT_MAX) flat = FLAT_MAX;  // k>=10000: B is zero there
            load16_to_lds(x + flat, &As32[(wv * 4 + i) * 8][0]);
        }
        float4 vh = *(const float4*)(whip + k0);
        float4 vl = *(const float4*)(wlop + k0);
        *(float4*)&Bs[0][bn][bp] = vh;
        *(float4*)&Bs[1][bn][bp] = vl;
        __syncthreads();

        frag_u ah[2], al[2];
#pragma unroll
        for (int r = 0; r < 2; r++) {
            int row = wv * 32 + r * 16 + lm;
            int r7 = row & 7;
            int s0 = (quad * 2) ^ r7;
            int s1 = (quad * 2 + 1) ^ r7;
            float4 fa = *(const float4*)&As32[row][s0 * 4];
            float4 fb = *(const float4*)&As32[row][s1 * 4];
            unsigned h0, l0, h1, l1, h2, l2, h3, l3;
            split2(fa.x, fa.y, h0, l0);
            split2(fa.z, fa.w, h1, l1);
            split2(fb.x, fb.y, h2, l2);
            split2(fb.z, fb.w, h3, l3);
            ah[r].i = make_int4((int)h0, (int)h1, (int)h2, (int)h3);
            al[r].i = make_int4((int)l0, (int)l1, (int)l2, (int)l3);
        }
        frag_u bh[4], bl[4];
#pragma unroll
        for (int c = 0; c < 4; c++) {
            int n = c * 16 + lm;
            bh[c].b = *(const bf16x8*)&Bs[0][n][quad * 8];
            bl[c].b = *(const bf16x8*)&Bs[1][n][quad * 8];
        }
#pragma unroll
        for (int r = 0; r < 2; r++)
#pragma unroll
            for (int c = 0; c < 4; c++) {
                acc[r][c] = __builtin_amdgcn_mfma_f32_16x16x32_bf16(al[r].b, bh[c].b, acc[r][c], 0, 0, 0);
                acc[r][c] = __builtin_amdgcn_mfma_f32_16x16x32_bf16(ah[r].b, bl[c].b, acc[r][c], 0, 0, 0);
                acc[r][c] = __builtin_amdgcn_mfma_f32_16x16x32_bf16(ah[r].b, bh[c].b, acc[r][c], 0, 0, 0);
            }
        __syncthreads();
    }

#pragma unroll
    for (int r = 0; r < 2; r++)
#pragma unroll
        for (int c = 0; c < 4; c++) {
            int row0 = m0 + wv * 32 + r * 16 + quad * 4;
            int cn = c * 16 + lm;
#pragma unroll
            for (int i = 0; i < 4; i++) {
                int gm = row0 + i;
                if (gm < N_NODES) atomicAdd(&out[gm * 64 + cn], acc[r][c][i]);
            }
        }
}

// ---------------- layer-1 aggregation (unchanged): agg(G1) + b1 + relu ----------------

__global__ void k_agg64(const float* __restrict__ h, const float* __restrict__ bias,
                        const int* __restrict__ roff, const int* __restrict__ csrc,
                        const float* __restrict__ cw, const float* __restrict__ dinv,
                        float* __restrict__ out, int do_relu) {
    int n = blockIdx.x * 4 + (threadIdx.x >> 6);
    int c = threadIdx.x & 63;
    float di = dinv[n];
    float acc = di * di * h[n * 64 + c];  // self-loop
    int e0 = roff[n], e1 = roff[n + 1];
    int e = e0;
    for (; e + 3 < e1; e += 4) {
        int s0 = csrc[e], s1 = csrc[e + 1], s2 = csrc[e + 2], s3 = csrc[e + 3];
        float w0 = cw[e], w1 = cw[e + 1], w2 = cw[e + 2], w3 = cw[e + 3];
        float v0 = h[s0 * 64 + c], v1 = h[s1 * 64 + c];
        float v2 = h[s2 * 64 + c], v3 = h[s3 * 64 + c];
        acc = fmaf(w0, v0, acc);
        acc = fmaf(w1, v1, acc);
        acc = fmaf(w2, v2, acc);
        acc = fmaf(w3, v3, acc);
    }
    for (; e < e1; e++)
        acc = fmaf(cw[e], h[csrc[e] * 64 + c], acc);
    acc += bias[c];
    if (do_relu) acc = fmaxf(acc, 0.f);
    out[n * 64 + c] = acc;
}

// ---------------- layer 2 fused: H2 = relu( (Â H1) · W2 + b2 ) ----------------
// Â commutes with right-mult by W2, so aggregate first (per-node wave), then
// do the 64x64 mat-vec in-wave from LDS. Deletes the standalone gemm64 dispatch
// and one 2.56 MB HBM round-trip.

__global__ __launch_bounds__(256) void k_layer2(
        const float* __restrict__ h, const float* __restrict__ W2,
        const float* __restrict__ b2,
        const int* __restrict__ roff, const int* __restrict__ csrc,
        const float* __restrict__ cw, const float* __restrict__ dinv,
        float* __restrict__ out) {
    __shared__ float Ws[64 * 64];     // 16 KB
    __shared__ float rowbuf[4][64];
    int tid = threadIdx.x;
    int w = tid >> 6, c = tid & 63;
    for (int f = tid; f < 1024; f += 256)
        *(float4*)&Ws[f * 4] = *(const float4*)&W2[f * 4];

    int n = blockIdx.x * 4 + w;
    float di = dinv[n];
    float acc = di * di * h[n * 64 + c];  // self-loop (agg of H1, no bias yet)
    int e0 = roff[n], e1 = roff[n + 1];
    int e = e0;
    for (; e + 3 < e1; e += 4) {
        int s0 = csrc[e], s1 = csrc[e + 1], s2 = csrc[e + 2], s3 = csrc[e + 3];
        float w0 = cw[e], w1 = cw[e + 1], w2 = cw[e + 2], w3 = cw[e + 3];
        float v0 = h[s0 * 64 + c], v1 = h[s1 * 64 + c];
        float v2 = h[s2 * 64 + c], v3 = h[s3 * 64 + c];
        acc = fmaf(w0, v0, acc);
        acc = fmaf(w1, v1, acc);
        acc = fmaf(w2, v2, acc);
        acc = fmaf(w3, v3, acc);
    }
    for (; e < e1; e++)
        acc = fmaf(cw[e], h[csrc[e] * 64 + c], acc);
    rowbuf[w][c] = acc;
    __syncthreads();  // covers Ws staging + rowbuf visibility

    float o = b2[c];
#pragma unroll
    for (int k = 0; k < 64; k++)
        o = fmaf(rowbuf[w][k], Ws[k * 64 + c], o);  // rowbuf: broadcast; Ws: stride-1
    o = fmaxf(o, 0.f);
    out[n * 64 + c] = o;
}

// ---------------- layer 3 fused: out = softmax( (Â H2) · W3 + b3 ) ----------------
// Same commute trick; 64x16 mat-vec split across 4 lane-groups + shuffle reduce,
// then in-wave softmax. Deletes gemm16 + agg16_softmax dispatches and bufC.

__global__ __launch_bounds__(256) void k_layer3(
        const float* __restrict__ h, const float* __restrict__ W3,
        const float* __restrict__ b3,
        const int* __restrict__ roff, const int* __restrict__ csrc,
        const float* __restrict__ cw, const float* __restrict__ dinv,
        float* __restrict__ out) {
    __shared__ float Ws[64 * 17];  // stride 17: kills the 4-way bank alias at stride 16
    __shared__ float rowbuf[4][64];
    int tid = threadIdx.x;
    int w = tid >> 6, c = tid & 63;
    for (int f = tid; f < 1024; f += 256) {
        int kk = f >> 4, cc0 = f & 15;
        Ws[kk * 17 + cc0] = W3[f];
    }

    int n = blockIdx.x * 4 + w;
    float di = dinv[n];
    float acc = di * di * h[n * 64 + c];
    int e0 = roff[n], e1 = roff[n + 1];
    int e = e0;
    for (; e + 3 < e1; e += 4) {
        int s0 = csrc[e], s1 = csrc[e + 1], s2 = csrc[e + 2], s3 = csrc[e + 3];
        float w0 = cw[e], w1 = cw[e + 1], w2 = cw[e + 2], w3 = cw[e + 3];
        float v0 = h[s0 * 64 + c], v1 = h[s1 * 64 + c];
        float v2 = h[s2 * 64 + c], v3 = h[s3 * 64 + c];
        acc = fmaf(w0, v0, acc);
        acc = fmaf(w1, v1, acc);
        acc = fmaf(w2, v2, acc);
        acc = fmaf(w3, v3, acc);
    }
    for (; e < e1; e++)
        acc = fmaf(cw[e], h[csrc[e] * 64 + c], acc);
    rowbuf[w][c] = acc;
    __syncthreads();

    // mat-vec: lane = cc + 16*g accumulates k in [16g, 16g+16)
    int cc = c & 15, g = c >> 4;
    float o = 0.f;
#pragma unroll
    for (int i = 0; i < 16; i++) {
        int k = g * 16 + i;
        o = fmaf(rowbuf[w][k], Ws[k * 17 + cc], o);
    }
    o += __shfl_xor(o, 16);
    o += __shfl_xor(o, 32);
    float logit = o + b3[cc];
    float m = logit;
    m = fmaxf(m, __shfl_xor(m, 1));
    m = fmaxf(m, __shfl_xor(m, 2));
    m = fmaxf(m, __shfl_xor(m, 4));
    m = fmaxf(m, __shfl_xor(m, 8));
    float ex = expf(logit - m);
    float s = ex;
    s += __shfl_xor(s, 1);
    s += __shfl_xor(s, 2);
    s += __shfl_xor(s, 4);
    s += __shfl_xor(s, 8);
    if (g == 0) out[n * 16 + cc] = ex / s;
}

// ---------------- launch ----------------

extern "C" void kernel_launch(void* const* d_in, const int* in_sizes, int n_in,
                              void* d_out, int out_size, void* d_ws, size_t ws_size,
                              hipStream_t stream) {
    (void)in_sizes; (void)n_in; (void)out_size; (void)ws_size;
    const float* x  = (const float*)d_in[0];
    const int*   ei = (const int*)d_in[1];
    const float* W1 = (const float*)d_in[2];
    const float* b1 = (const float*)d_in[3];
    const float* W2 = (const float*)d_in[4];
    const float* b2 = (const float*)d_in[5];
    const float* W3 = (const float*)d_in[6];
    const float* b3 = (const float*)d_in[7];
    float* out = (float*)d_out;
    const int* esrc = ei;
    const int* edst = ei + E_EDGES;

    char* p = (char*)d_ws;
    size_t off = 0;
    auto alloc = [&](size_t b) -> void* {
        void* r = p + off;
        off += (b + 255) & ~(size_t)255;
        return r;
    };
    // deg | cursor | bufA laid out contiguously -> ONE memset covers all three
    int*    deg    = (int*)alloc(N_NODES * 4);
    int*    cursor = (int*)alloc(N_NODES * 4);
    float*  bufA   = (float*)alloc(N_NODES * 64 * 4);
    int*    roff   = (int*)alloc((N_NODES + 1) * 4);
    float*  dinv   = (float*)alloc(N_NODES * 4);
    int*    csrc   = (int*)alloc(E_EDGES * 4);
    float*  cw     = (float*)alloc(E_EDGES * 4);
    float*  bufB   = (float*)alloc(N_NODES * 64 * 4);
    ushort* Whi    = (ushort*)alloc((size_t)64 * KP * 2);
    ushort* Wlo    = (ushort*)alloc((size_t)64 * KP * 2);

    size_t zlen = (size_t)((char*)(bufA + N_NODES * 64) - (char*)deg);
    hipMemsetAsync(deg, 0, zlen, stream);  // deg + cursor + gemm1 split-K accumulator

    // setup: histogram + W1 split fused (independent halves, disjoint block ranges)
    k_hist_wsplit<<<HIST_BLOCKS + WSPLIT_BLOCKS, 256, 0, stream>>>(edst, deg, W1, Whi, Wlo);
    k_scan<<<1, 256, 0, stream>>>(deg, roff, dinv);
    k_scatter<<<(E_EDGES + 255) / 256, 256, 0, stream>>>(esrc, edst, roff, cursor, dinv,
                                                         csrc, cw);

    // layer 1: G1 = X*W1 (split-K MFMA, atomic accumulate), then agg + b1 + relu
    k_gemm1_mfma<<<dim3((N_NODES + G1_BM - 1) / G1_BM, G1_NCHUNK), 256, 0, stream>>>(
        x, Whi, Wlo, bufA);
    k_agg64<<<N_NODES / 4, 256, 0, stream>>>(bufA, b1, roff, csrc, cw, dinv, bufB, 1);
    // layer 2 fused: H2 = relu((Â H1) W2 + b2)
    k_layer2<<<N_NODES / 4, 256, 0, stream>>>(bufB, W2, b2, roff, csrc, cw, dinv, bufA);
    // layer 3 fused: out = softmax((Â H2) W3 + b3)
    k_layer3<<<N_NODES / 4, 256, 0, stream>>>(bufA, W3, b3, roff, csrc, cw, dinv, out);
}